// Round 10
// baseline (232.903 us; speedup 1.0000x reference)
//
#include <hip/hip_runtime.h>
#include <hip/hip_bf16.h>
#include <math.h>

#define B 64
#define S 2048
#define H 512
#define BS (B * S)

// workspace layout (floats)
#define QS_OFF 0                          // qs: B*H
#define SP_OFF (B * H)                    // score partials: 4 * B*S
#define PC_OFF (B * H + 4 * B * S)        // pc: B*NCHUNK*H  (Wt aliases, used before pc)
#define NCHUNK 16
#define CHUNK  128                        // S / NCHUNK

typedef __attribute__((ext_vector_type(8))) short short8;
typedef __attribute__((ext_vector_type(4))) float f32x4;

static __device__ __forceinline__ short f2bf(float f) {
    union { float f; unsigned u; } x; x.f = f;
    unsigned r = x.u + 0x7fffu + ((x.u >> 16) & 1u);   // RNE
    return (short)(r >> 16);
}

static __device__ __forceinline__ float ftanh(float x) {
    x = fminf(fmaxf(x, -30.f), 30.f);
    const float e = __builtin_amdgcn_exp2f(x * 2.8853900817779268f); // e^(2x)
    return (e - 1.f) * __builtin_amdgcn_rcpf(e + 1.f);
}

static __device__ __forceinline__ short8 cvt8(float4 a, float4 b) {
    union { short8 s; __hip_bfloat162 h[4]; } u;
    u.h[0] = __float22bfloat162_rn(make_float2(a.x, a.y));
    u.h[1] = __float22bfloat162_rn(make_float2(a.z, a.w));
    u.h[2] = __float22bfloat162_rn(make_float2(b.x, b.y));
    u.h[3] = __float22bfloat162_rn(make_float2(b.z, b.w));
    return u.s;
}

#define GLL16(g_, l_) __builtin_amdgcn_global_load_lds(                        \
    (const __attribute__((address_space(1))) void*)(g_),                      \
    (__attribute__((address_space(3))) void*)(l_), 16, 0, 0)

// ---------------- kernel 1: q_scores = query @ W_s (B,H) ----------------
__global__ __launch_bounds__(512) void qs_kernel(const float* __restrict__ query,
                                                 const float* __restrict__ W_s,
                                                 float* __restrict__ qs) {
    const int b = blockIdx.x, k = threadIdx.x;
    __shared__ float q[H];
    q[k] = query[b * H + k];
    __syncthreads();
    float acc = 0.f;
#pragma unroll 8
    for (int h = 0; h < H; ++h) acc = fmaf(q[h], W_s[h * H + k], acc);
    qs[b * H + k] = acc;
}

// -------- kernel 1b: W_h -> bf16 fragment-ordered Wt --------
// layout: [step 16][wc 4][cb 8][lane 64][j 8] shorts
// element = W_h[k][col], k = step*32 + (lane>>4)*8 + j, col = wc*128 + cb*16 + (lane&15)
__global__ __launch_bounds__(256) void wt_prep(const float* __restrict__ W_h,
                                               short* __restrict__ Wt) {
    const int idx = blockIdx.x * 256 + threadIdx.x;       // 0 .. 262143
    const int j  = idx & 7;
    const int l  = (idx >> 3) & 63;
    const int cb = (idx >> 9) & 7;
    const int wc = (idx >> 12) & 3;
    const int st = idx >> 14;
    const int k   = st * 32 + (l >> 4) * 8 + j;
    const int col = wc * 128 + cb * 16 + (l & 15);
    Wt[idx] = f2bf(W_h[k * H + col]);
}

// ------- kernel 2: scores partials — B-resident LDS, barrier-free K-loop -------
// 1024 blocks: xcd = bid&7, j = bid>>3, cg = j&3 (128-col group), rblk = j>>2.
// All 4 cg-blocks of the same rows land on the same XCD (L2-local enc reads).
// Per block: load B slice (512x128 bf16 = 128 KB) to LDS ONCE, one barrier,
// then 8 independent waves each stream 32-row tiles: A global->reg (depth-2
// prefetch), 8 ds_read + 16 MFMA per k-step, NO barriers, NO cross-wave sync.
__global__ __launch_bounds__(512, 2) void scores_mfma_kernel(const float* __restrict__ enc,
                                                             const short* __restrict__ Wt,
                                                             const float* __restrict__ v,
                                                             const int* __restrict__ lens,
                                                             const float* __restrict__ qs,
                                                             float* __restrict__ sp) {
    const int t = threadIdx.x;
    const int w = t >> 6, l = t & 63;
    const int g = l >> 4, c = l & 15;
    const int bid = blockIdx.x;
    const int xcd = bid & 7, j = bid >> 3;
    const int cg = j & 3, rblk = j >> 2;

    __shared__ __attribute__((aligned(16))) char Bs[131072];   // 128 KB B slice

    // one-time B load: per st, 8192 B, 512 thr x 16 B
    {
        const char* WtB = (const char*)Wt;
#pragma unroll
        for (int st = 0; st < 16; ++st)
            GLL16(WtB + (size_t)(st * 4 + cg) * 8192 + t * 16, Bs + st * 8192 + t * 16);
    }
    __syncthreads();

    float vreg[8];
#pragma unroll
    for (int cb = 0; cb < 8; ++cb) vreg[cb] = v[cg * 128 + cb * 16 + c];

    const int base_tile = (xcd * 32 + rblk) * 8 + w;   // [0, 2048)

    for (int i = 0; i < 2; ++i) {
        const int tile = base_tile + i * 2048;         // [0, 4096)
        const int b  = tile >> 6;
        const int tt = tile & 63;
        const int s0 = ((tt + b) & 63) * 32;           // staggered row-tile
        if (s0 >= lens[b]) continue;

        float qreg[8];
#pragma unroll
        for (int cb = 0; cb < 8; ++cb) qreg[cb] = qs[b * H + cg * 128 + cb * 16 + c];

        const float* agA = enc + (size_t)(b * S + s0) * H;

        // depth-2 A prefetch, all statically indexed (full unroll)
        float4 pf[2][2][2];
#pragma unroll
        for (int rb = 0; rb < 2; ++rb) {
            const float* p0 = agA + (rb * 16 + c) * H + g * 8;
            pf[0][rb][0] = *(const float4*)(p0);
            pf[0][rb][1] = *(const float4*)(p0 + 4);
            pf[1][rb][0] = *(const float4*)(p0 + 32);
            pf[1][rb][1] = *(const float4*)(p0 + 36);
        }

        f32x4 acc[2][8];
        const f32x4 z = {0.f, 0.f, 0.f, 0.f};
#pragma unroll
        for (int rb = 0; rb < 2; ++rb)
#pragma unroll
            for (int cb = 0; cb < 8; ++cb) acc[rb][cb] = z;

#pragma unroll
        for (int st = 0; st < 16; ++st) {
            const short8 af0 = cvt8(pf[st & 1][0][0], pf[st & 1][0][1]);
            const short8 af1 = cvt8(pf[st & 1][1][0], pf[st & 1][1][1]);
            if (st < 14) {
#pragma unroll
                for (int rb = 0; rb < 2; ++rb) {
                    const float* pn = agA + (rb * 16 + c) * H + (st + 2) * 32 + g * 8;
                    pf[st & 1][rb][0] = *(const float4*)(pn);
                    pf[st & 1][rb][1] = *(const float4*)(pn + 4);
                }
            }
#pragma unroll
            for (int cb = 0; cb < 8; ++cb) {
                const short8 bf = *(const short8*)(Bs + st * 8192 + cb * 1024 + l * 16);
                acc[0][cb] = __builtin_amdgcn_mfma_f32_16x16x32_bf16(af0, bf, acc[0][cb], 0, 0, 0);
                acc[1][cb] = __builtin_amdgcn_mfma_f32_16x16x32_bf16(af1, bf, acc[1][cb], 0, 0, 0);
            }
        }

        // epilogue: partial p[row] = sum over this cg's 128 cols of v*tanh(e+qs)
        float part[2][4];
#pragma unroll
        for (int rb = 0; rb < 2; ++rb)
#pragma unroll
            for (int r = 0; r < 4; ++r) part[rb][r] = 0.f;
#pragma unroll
        for (int cb = 0; cb < 8; ++cb)
#pragma unroll
            for (int rb = 0; rb < 2; ++rb)
#pragma unroll
                for (int r = 0; r < 4; ++r)
                    part[rb][r] += vreg[cb] * ftanh(acc[rb][cb][r] + qreg[cb]);
        // reduce across the 16 c-lanes (wave-local; rows live at (g, r))
#pragma unroll
        for (int m = 1; m < 16; m <<= 1)
#pragma unroll
            for (int rb = 0; rb < 2; ++rb)
#pragma unroll
                for (int r = 0; r < 4; ++r)
                    part[rb][r] += __shfl_xor(part[rb][r], m);
        if (c == 0) {
            float* spb = sp + (size_t)cg * BS + b * S + s0;
#pragma unroll
            for (int rb = 0; rb < 2; ++rb)
#pragma unroll
                for (int r = 0; r < 4; ++r)
                    spb[rb * 16 + g * 4 + r] = part[rb][r];
        }
    }
}

// ------ kernel 3: masked softmax over S (sums 4 col-group partials), write attn ------
__global__ __launch_bounds__(256) void softmax_kernel(const float* __restrict__ sp,
                                                      const int* __restrict__ lens,
                                                      float* __restrict__ attn) {
    const int b = blockIdx.x, t = threadIdx.x;
    const int len = lens[b];
    const int wave = t >> 6, lane = t & 63;
    __shared__ float red[4];

    float vals[8];
    float m = -INFINITY;
#pragma unroll
    for (int i = 0; i < 8; ++i) {
        const int s = i * 256 + t;
        if (s < len) {
            const size_t o = (size_t)b * S + s;
            vals[i] = sp[o] + sp[BS + o] + sp[2 * BS + o] + sp[3 * BS + o];
        } else vals[i] = -INFINITY;
        m = fmaxf(m, vals[i]);
    }
#pragma unroll
    for (int off = 32; off > 0; off >>= 1) m = fmaxf(m, __shfl_down(m, off));
    if (lane == 0) red[wave] = m;
    __syncthreads();
    m = fmaxf(fmaxf(red[0], red[1]), fmaxf(red[2], red[3]));
    __syncthreads();

    float e[8];
    float sum = 0.f;
#pragma unroll
    for (int i = 0; i < 8; ++i) {
        const int s = i * 256 + t;
        e[i] = (s < len) ? expf(vals[i] - m) : 0.f;
        sum += e[i];
    }
#pragma unroll
    for (int off = 32; off > 0; off >>= 1) sum += __shfl_down(sum, off);
    if (lane == 0) red[wave] = sum;
    __syncthreads();
    const float inv = 1.f / (red[0] + red[1] + red[2] + red[3]);
#pragma unroll
    for (int i = 0; i < 8; ++i) attn[b * S + i * 256 + t] = e[i] * inv;
}

// -------- kernel 4a: partial context sums over s-chunks (masked skipped) --------
__global__ __launch_bounds__(256) void ctx_partial_kernel(const float* __restrict__ enc,
                                                          const float* __restrict__ attn,
                                                          const int* __restrict__ lens,
                                                          float* __restrict__ pc) {
    const int b = blockIdx.x >> 4, ch = blockIdx.x & 15;
    const int len = lens[b];
    const int sbase = ch * CHUNK;
    if (sbase >= len) return;
    const int ns = min(CHUNK, len - sbase);
    const int t = threadIdx.x;

    __shared__ float alds[CHUNK];
    if (t < CHUNK) alds[t] = (t < ns) ? attn[b * S + sbase + t] : 0.f;
    __syncthreads();

    const float2* e2 = (const float2*)(enc + (size_t)(b * S + sbase) * H);
    float2 acc = make_float2(0.f, 0.f);
    for (int s = 0; s < ns; ++s) {
        const float a = alds[s];
        const float2 e = e2[s * 256 + t];
        acc.x = fmaf(a, e.x, acc.x);
        acc.y = fmaf(a, e.y, acc.y);
    }
    ((float2*)(pc + (size_t)(b * NCHUNK + ch) * H))[t] = acc;
}

// ------ kernel 4b: context reduce + w_out = tanh([ctx, q] @ W_out) ------
__global__ __launch_bounds__(512) void out_kernel(const float* __restrict__ pc,
                                                  const float* __restrict__ query,
                                                  const float* __restrict__ W_out,
                                                  const int* __restrict__ lens,
                                                  float* __restrict__ wout) {
    const int b = blockIdx.x, k = threadIdx.x;
    const int len = lens[b];
    const int nch = (len + CHUNK - 1) / CHUNK;
    __shared__ float cat[2 * H];
    float ctx = 0.f;
    for (int ch = 0; ch < nch; ++ch) ctx += pc[(size_t)(b * NCHUNK + ch) * H + k];
    cat[k] = ctx;
    cat[H + k] = query[b * H + k];
    __syncthreads();
    float acc = 0.f;
#pragma unroll 8
    for (int cI = 0; cI < 2 * H; ++cI) acc = fmaf(cat[cI], W_out[cI * H + k], acc);
    wout[b * H + k] = tanhf(acc);
}

extern "C" void kernel_launch(void* const* d_in, const int* in_sizes, int n_in,
                              void* d_out, int out_size, void* d_ws, size_t ws_size,
                              hipStream_t stream) {
    const float* query = (const float*)d_in[0];
    const float* enc   = (const float*)d_in[1];
    const int*   lens  = (const int*)d_in[2];
    const float* W_h   = (const float*)d_in[3];
    const float* W_s   = (const float*)d_in[4];
    const float* v     = (const float*)d_in[5];
    const float* W_out = (const float*)d_in[6];

    float* out  = (float*)d_out;
    float* wout = out;          // B*H
    float* attn = out + B * H;  // B*S

    float* ws = (float*)d_ws;
    float* qs = ws + QS_OFF;
    float* sp = ws + SP_OFF;
    float* pc = ws + PC_OFF;
    short* Wt = (short*)(ws + PC_OFF);   // aliases pc: Wt used in scores (before pc written)

    qs_kernel<<<B, H, 0, stream>>>(query, W_s, qs);
    wt_prep<<<1024, 256, 0, stream>>>(W_h, Wt);
    scores_mfma_kernel<<<1024, 512, 0, stream>>>(enc, Wt, v, lens, qs, sp);
    softmax_kernel<<<B, 256, 0, stream>>>(sp, lens, attn);
    ctx_partial_kernel<<<B * NCHUNK, 256, 0, stream>>>(enc, attn, lens, pc);
    out_kernel<<<B, H, 0, stream>>>(pc, query, W_out, lens, wout);
}